// Round 14
// baseline (205.779 us; speedup 1.0000x reference)
//
#include <hip/hip_runtime.h>
#include <math.h>

#define BI 64
#define RR 36
#define BC 64
#define WW 50
#define DD 512
#define HH 256
#define CST 132

typedef _Float16 f16x8 __attribute__((ext_vector_type(8)));
typedef _Float16 f16x4 __attribute__((ext_vector_type(4)));
typedef float    f32x4 __attribute__((ext_vector_type(4)));

__device__ __forceinline__ float wave_sum(float v){
  #pragma unroll
  for (int off=32; off>0; off>>=1) v += __shfl_xor(v, off, 64);
  return v;
}
__device__ __forceinline__ float wave_max(float v){
  #pragma unroll
  for (int off=32; off>0; off>>=1) v = fmaxf(v, __shfl_xor(v, off, 64));
  return v;
}

// ---------------------------------------------------------------------------
// PrepGram (r13 replay-verified): fused independent producers.
//  bx < 1504 : prep3 body — split fp32 -> f16 hi + lo*2048 frags.
//  bx >= 1504: gram body — fp32 G + f16 B-frag Gfrag (ones col at n==50).
// ---------------------------------------------------------------------------
__global__ __launch_bounds__(256) void prepgram_kernel(
    const float* __restrict__ imgs, const float* __restrict__ caps,
    const float* __restrict__ sw1, const float* __restrict__ hw1,
    _Float16* __restrict__ Ah, _Float16* __restrict__ Al,
    _Float16* __restrict__ Bh, _Float16* __restrict__ Bl,
    float* __restrict__ G, _Float16* __restrict__ Gfrag)
{
  __shared__ __align__(16) float smem[WW*CST + 1024];   // gram branch only
  if (blockIdx.x < 1504){
    int u = blockIdx.x*256 + threadIdx.x;
    _Float16 *dh, *dl; int idx;
    if (u < 144*1024){ idx = u;            dh = Ah; dl = Al; }
    else             { idx = u - 144*1024; dh = Bh; dl = Bl; }
    const int tile = idx >> 10, rem = idx & 1023, ks = rem >> 6, lane = rem & 63;
    const int k0 = ks*32 + (lane >> 4)*8;
    f16x8 hv, lv;
    if (u < 144*1024 || tile < 200){
      const float* src = (u < 144*1024) ? imgs : caps;
      const int m = tile*16 + (lane & 15);
      const float* p = src + (size_t)m*DD + k0;
      #pragma unroll
      for (int j=0;j<8;j++){
        float a = p[j];
        _Float16 h = (_Float16)a;
        hv[j] = h;
        lv[j] = (_Float16)((a - (float)h) * 2048.0f);
      }
    } else {
      const int n = (tile-200)*16 + (lane & 15);          // 0..511
      const float* src = (n < HH) ? (sw1 + n) : (hw1 + n - HH);
      #pragma unroll
      for (int j=0;j<8;j++){
        float a = src[(size_t)(k0+j)*HH];
        _Float16 h = (_Float16)a;
        hv[j] = h;
        lv[j] = (_Float16)((a - (float)h) * 2048.0f);
      }
    }
    *(f16x8*)(dh + (size_t)idx*8) = hv;
    *(f16x8*)(dl + (size_t)idx*8) = lv;
  } else {
    float* cs = smem;
    float* Gt = smem + WW*CST;
    const int bxg  = blockIdx.x - 1504;
    const int c    = bxg >> 2;
    const int tile = bxg & 3;
    const int w0   = tile*16;
    const int nw   = (tile==3) ? 2 : 16;
    const int t=threadIdx.x, lane=t&63, wv=t>>6;
    const int wl = lane < WW ? lane : WW-1;
    float acc[4]={0.f,0.f,0.f,0.f};
    for (int k0=0;k0<DD;k0+=128){
      __syncthreads();
      for (int n=t;n<WW*32;n+=256){
        int row=n>>5, c4=(n&31)*4;
        *(float4*)&cs[row*CST+c4] = *(const float4*)(caps + ((size_t)c*WW+row)*DD + k0 + c4);
      }
      __syncthreads();
      for (int k=0;k<128;k+=4){
        float4 cv = *(const float4*)&cs[wl*CST+k];
        #pragma unroll
        for (int q=0;q<4;q++){
          int lw = wv + q*4;
          if (lw < nw){
            float4 bv = *(const float4*)&cs[(w0+lw)*CST+k];
            acc[q]=fmaf(bv.x,cv.x,acc[q]); acc[q]=fmaf(bv.y,cv.y,acc[q]);
            acc[q]=fmaf(bv.z,cv.z,acc[q]); acc[q]=fmaf(bv.w,cv.w,acc[q]);
          }
        }
      }
    }
    for (int n=t;n<1024;n+=256) Gt[n]=0.f;
    __syncthreads();
    if (lane < WW){
      #pragma unroll
      for (int q=0;q<4;q++){
        int lw = wv + q*4;
        if (lw < nw){
          G[(size_t)c*WW*WW + (w0+lw)*WW + lane] = acc[q];
          Gt[lw*64 + lane] = acc[q];
        }
      }
    }
    __syncthreads();
    {
      int flat = t*4;
      int ks = flat>>9, L=(flat>>3)&63, j0=flat&7;
      const bool ones = (tile==3) && ((L&15)==2);   // frag n == 50
      f16x4 v;
      #pragma unroll
      for (int e=0;e<4;e++)
        v[e] = ones ? (_Float16)1.0f
                    : (_Float16)Gt[(L&15)*64 + ks*32 + ((L>>4)<<3) + j0 + e];
      *(f16x4*)&Gfrag[(size_t)c*4096 + (tile*2+ks)*512 + L*8 + j0] = v;
    }
  }
}

// ---------------------------------------------------------------------------
// Hgemm (r12/r13 replay-verified): H = Ah @ W (raw; bias+relu in greduce).
// ---------------------------------------------------------------------------
__global__ __launch_bounds__(256) void hgemm_kernel(
    const _Float16* __restrict__ Ah, const _Float16* __restrict__ Bh,
    float* __restrict__ H)
{
  __shared__ _Float16 lds[8192];
  const int t = threadIdx.x, lane = t & 63, wv = t >> 6;
  const int mb = blockIdx.x % 18, nb = blockIdx.x / 18;
  const int wm = wv & 1, wn = wv >> 1;

  f32x4 P[4][4];
  #pragma unroll
  for (int a=0;a<4;a++)
    #pragma unroll
    for (int b=0;b<4;b++) P[a][b]=(f32x4){0,0,0,0};

  const _Float16* sbase = (wv < 2) ? Ah : (Bh + (size_t)200*8192);
  const size_t tb = (size_t)((wv < 2) ? mb : nb)*8 + (size_t)(wv & 1)*4;
  _Float16* ldst = lds + ((wv >= 2) ? 4096 : 0) + (wv & 1)*2048;

  for (int ks=0; ks<16; ks++){
    int4 v[4];
    #pragma unroll
    for (int s=0;s<4;s++)
      v[s] = *(const int4*)(sbase + (((tb+s)*16 + ks)*64 + lane)*8);
    #pragma unroll
    for (int s=0;s<4;s++)
      *(int4*)&ldst[s*512 + lane*8] = v[s];
    __syncthreads();
    f16x8 a[4], b[4];
    #pragma unroll
    for (int x=0;x<4;x++){
      a[x] = *(const f16x8*)&lds[       (wm*4+x)*512 + lane*8];
      b[x] = *(const f16x8*)&lds[4096 + (wn*4+x)*512 + lane*8];
    }
    #pragma unroll
    for (int mi=0;mi<4;mi++)
      #pragma unroll
      for (int ni=0;ni<4;ni++)
        P[mi][ni] = __builtin_amdgcn_mfma_f32_16x16x32_f16(a[mi], b[ni], P[mi][ni],0,0,0);
    __syncthreads();
  }

  const int r0 = mb*128 + wm*64 + ((lane>>4)<<2);
  const int c0 = nb*128 + wn*64 + (lane&15);
  #pragma unroll
  for (int ni=0;ni<4;ni++){
    int col = c0 + ni*16;
    #pragma unroll
    for (int mi=0;mi<4;mi++)
      #pragma unroll
      for (int reg=0;reg<4;reg++)
        H[(size_t)(r0 + mi*16 + reg)*512 + col] = P[mi][ni][reg];
  }
}

// ---------------------------------------------------------------------------
// Greduce v2 (r12/r13 replay-verified): gates from raw H (bias+relu here).
// ---------------------------------------------------------------------------
__global__ __launch_bounds__(256) void greduce_kernel(
    const float* __restrict__ H, const float* __restrict__ imgs,
    const float* __restrict__ sb1, const float* __restrict__ hb1,
    const float* __restrict__ sw2, const float* __restrict__ hw2,
    const float* __restrict__ sb2, const float* __restrict__ hb2,
    float* __restrict__ sgn, float* __restrict__ hgn, float* __restrict__ rn)
{
  const int r = blockIdx.x*4 + (threadIdx.x >> 6);
  const int lane = threadIdx.x & 63;
  float4 hs = *(const float4*)&H[(size_t)r*512 + lane*4];
  float4 bs = *(const float4*)&sb1[lane*4];
  float4 ws = *(const float4*)&sw2[lane*4];
  float4 hh = *(const float4*)&H[(size_t)r*512 + 256 + lane*4];
  float4 bh = *(const float4*)&hb1[lane*4];
  float4 wh = *(const float4*)&hw2[lane*4];
  float ds = fmaxf(hs.x+bs.x,0.f)*ws.x + fmaxf(hs.y+bs.y,0.f)*ws.y
           + fmaxf(hs.z+bs.z,0.f)*ws.z + fmaxf(hs.w+bs.w,0.f)*ws.w;
  float dh = fmaxf(hh.x+bh.x,0.f)*wh.x + fmaxf(hh.y+bh.y,0.f)*wh.y
           + fmaxf(hh.z+bh.z,0.f)*wh.z + fmaxf(hh.w+bh.w,0.f)*wh.w;
  float4 x0 = *(const float4*)&imgs[(size_t)r*512 + lane*8];
  float4 x1 = *(const float4*)&imgs[(size_t)r*512 + lane*8 + 4];
  float ss = x0.x*x0.x+x0.y*x0.y+x0.z*x0.z+x0.w*x0.w
           + x1.x*x1.x+x1.y*x1.y+x1.z*x1.z+x1.w*x1.w;
  ds = wave_sum(ds); dh = wave_sum(dh); ss = wave_sum(ss);
  if (lane == 0){
    float s = 1.f/(1.f+__expf(-(ds + sb2[0])));
    float h = 1.f/(1.f+__expf(-(dh + hb2[0])));
    float tot = s + h + 1e-8f;
    sgn[r] = s/tot; hgn[r] = h/tot;
    rn[r]  = 1.f/fmaxf(sqrtf(ss), 1e-12f);
  }
}

// ---------------------------------------------------------------------------
// S GEMM v5 (hybrid): hi fragments via dbuf LDS (2 x 16KB — halves LDS-pipe
// traffic, the measured bottleneck); lo fragments straight from global (they
// are already in MFMA lane order; 16B/lane coalesced, L2-resident). P-MFMAs
// (hi-only) issue first each step to cover lo load latency. Grid 18x25=450
// (all co-resident at 2 blocks/CU). Values identical to r13.
// ---------------------------------------------------------------------------
__global__ __launch_bounds__(256) void sgemm_kernel(
    const _Float16* __restrict__ Ah, const _Float16* __restrict__ Al,
    const _Float16* __restrict__ Bh, const _Float16* __restrict__ Bl,
    float* __restrict__ Sp)
{
  __shared__ _Float16 lds[2*8192];   // per buffer: Ah 8 tiles + Bh 8 tiles
  const int t = threadIdx.x, lane = t & 63, wv = t >> 6;
  const int mb = blockIdx.x % 18, nb = blockIdx.x / 18;
  const int wm = wv & 1, wn = wv >> 1;

  f32x4 P[4][4], Q[4][4];
  #pragma unroll
  for (int a=0;a<4;a++)
    #pragma unroll
    for (int b=0;b<4;b++){ P[a][b]=(f32x4){0,0,0,0}; Q[a][b]=(f32x4){0,0,0,0}; }

  // hi staging: waves 0,1 stage Ah tiles, waves 2,3 stage Bh tiles (4 each)
  const _Float16* sbase = (wv < 2) ? Ah : Bh;
  const size_t tb = (size_t)((wv < 2) ? mb : nb)*8 + (size_t)(wv & 1)*4;

  int4 v[4];
  #pragma unroll
  for (int s=0;s<4;s++)
    v[s] = *(const int4*)(sbase + (((tb+s)*16 + 0)*64 + lane)*8);
  {
    _Float16* ldst = lds + wv*2048;
    #pragma unroll
    for (int s=0;s<4;s++)
      *(int4*)&ldst[s*512 + lane*8] = v[s];
  }
  __syncthreads();

  // lo fragment pointers (global, fragment order, 16B/lane)
  const _Float16* pAl = Al + (size_t)(mb*8 + wm*4)*8192 + lane*8;
  const _Float16* pBl = Bl + (size_t)(nb*8 + wn*4)*8192 + lane*8;

  for (int ks=0; ks<16; ks++){
    // current step's lo frags straight from global (latency covered by P phase)
    f16x8 a_l[4], b_l[4];
    #pragma unroll
    for (int x=0;x<4;x++){
      a_l[x] = *(const f16x8*)(pAl + (size_t)x*8192 + (size_t)ks*512);
      b_l[x] = *(const f16x8*)(pBl + (size_t)x*8192 + (size_t)ks*512);
    }
    // next step's hi prefetch (registers -> LDS after compute)
    if (ks < 15){
      #pragma unroll
      for (int s=0;s<4;s++)
        v[s] = *(const int4*)(sbase + (((tb+s)*16 + (ks+1))*64 + lane)*8);
    }

    const _Float16* L = lds + (ks & 1)*8192;
    f16x8 a_h[4], b_h[4];
    #pragma unroll
    for (int x=0;x<4;x++){
      a_h[x] = *(const f16x8*)&L[       (wm*4+x)*512 + lane*8];
      b_h[x] = *(const f16x8*)&L[4096 + (wn*4+x)*512 + lane*8];
    }
    // P first: hi-only, no dependence on lo loads
    #pragma unroll
    for (int mi=0;mi<4;mi++)
      #pragma unroll
      for (int ni=0;ni<4;ni++)
        P[mi][ni] = __builtin_amdgcn_mfma_f32_16x16x32_f16(a_h[mi], b_h[ni], P[mi][ni],0,0,0);
    #pragma unroll
    for (int mi=0;mi<4;mi++)
      #pragma unroll
      for (int ni=0;ni<4;ni++){
        Q[mi][ni] = __builtin_amdgcn_mfma_f32_16x16x32_f16(a_h[mi], b_l[ni], Q[mi][ni],0,0,0);
        Q[mi][ni] = __builtin_amdgcn_mfma_f32_16x16x32_f16(a_l[mi], b_h[ni], Q[mi][ni],0,0,0);
      }

    if (ks < 15){
      _Float16* ldst = lds + ((ks+1) & 1)*8192 + wv*2048;
      #pragma unroll
      for (int s=0;s<4;s++)
        *(int4*)&ldst[s*512 + lane*8] = v[s];
    }
    __syncthreads();
  }

  const int r0 = mb*128 + wm*64 + ((lane>>4)<<2);
  const int c0 = nb*128 + wn*64 + (lane&15);
  size_t pr[16]; size_t pc[4];
  #pragma unroll
  for (int mi=0;mi<4;mi++)
    #pragma unroll
    for (int reg=0;reg<4;reg++){
      unsigned row = (unsigned)(r0 + mi*16 + reg);
      unsigned i = row / 36u, rr_ = row - i*36u;
      pr[mi*4+reg] = (size_t)i*115200u + (size_t)rr_*50u;
    }
  #pragma unroll
  for (int ni=0;ni<4;ni++){
    unsigned col = (unsigned)(c0 + ni*16);
    unsigned cc = col / 50u, w = col - cc*50u;
    pc[ni] = (size_t)cc*1800u + w;
  }
  #pragma unroll
  for (int mi=0;mi<4;mi++)
    #pragma unroll
    for (int ni=0;ni<4;ni++)
      #pragma unroll
      for (int reg=0;reg<4;reg++)
        Sp[pr[mi*4+reg] + pc[ni]] =
            P[mi][ni][reg] + Q[mi][ni][reg]*(1.0f/2048.0f);
}

// ---------------------------------------------------------------------------
// Epilogue v3 (r8..r13 replay-verified, verbatim).
// ---------------------------------------------------------------------------
__global__ __launch_bounds__(512) void epi_kernel(
    const float* __restrict__ Sp,
    const int* __restrict__ img_lens, const int* __restrict__ cap_lens,
    const float* __restrict__ sgn, const float* __restrict__ hgn,
    const float* __restrict__ rn,
    const float* __restrict__ G, const _Float16* __restrict__ Gfrag,
    float* __restrict__ out)
{
  __shared__ __align__(16) _Float16 sEp[48*72];
  __shared__ __align__(16) _Float16 sE2[48*72];
  __shared__ __align__(16) _Float16 sFp[48*72];
  __shared__ __align__(16) _Float16 sGf[4096];
  __shared__ float sTd[48];
  __shared__ float sTS[48];
  __shared__ float sGd[64];

  const int bx = blockIdx.x;
  const int i = bx >> 6, c = bx & 63;
  const int t = threadIdx.x, lane = t & 63;
  const int wv = __builtin_amdgcn_readfirstlane(t >> 6);   // 0..7
  const int cap_len = cap_lens[c];
  const int img_len = img_lens[i];

  ((int4*)sGf)[t] = ((const int4*)(Gfrag + (size_t)c*4096))[t];
  if (t < WW) sGd[t] = G[(size_t)c*WW*WW + t*(WW+1)];
  if (t < 96){
    int row = 36 + (t>>3), col8 = (t&7)*8;
    *(int4*)&sEp[row*72 + col8] = (int4){0,0,0,0};
    *(int4*)&sE2[row*72 + col8] = (int4){0,0,0,0};
  }

  const int r0  = (wv < 4) ? wv*5 : 20 + (wv-4)*4;
  const int cnt = (wv < 4) ? 5 : 4;

  const float* srow = Sp + (size_t)(i*64 + c)*1800u + (size_t)r0*50;
  float avA[5]; int aiA[5];
  #pragma unroll 5
  for (int j=0;j<cnt;j++){
    const int r = r0 + j;
    float s = (lane < WW) ? srow[j*50 + lane] : 0.f;
    const bool valid = (lane < cap_len);
    float av = wave_max(valid ? s : -INFINITY);
    unsigned long long m = __ballot(valid && (s == av));
    int ai = (int)(__ffsll((long long)m) - 1);
    float e = valid ? __expf(10.0f*(s - av)) : 0.f;
    avA[j] = av; aiA[j] = ai;
    sEp[r*72 + lane] = (_Float16)e;
    sE2[r*72 + lane] = (_Float16)(e * s);
  }
  __syncthreads();

  {
    int mi = wv % 3, nt = wv / 3;
    f32x4 acc = (f32x4){0,0,0,0};
    #pragma unroll
    for (int ks=0; ks<2; ks++){
      f16x8 a = *(const f16x8*)&sEp[(mi*16+(lane&15))*72 + ks*32 + ((lane>>4)<<3)];
      f16x8 b = *(const f16x8*)&sGf[(nt*2+ks)*512 + lane*8];
      acc = __builtin_amdgcn_mfma_f32_16x16x32_f16(a, b, acc, 0,0,0);
    }
    #pragma unroll
    for (int reg=0; reg<4; reg++){
      int row = mi*16 + ((lane>>4)<<2) + reg;
      sFp[row*72 + nt*16 + (lane&15)] = (_Float16)acc[reg];
    }
  }
  if (wv < 4){
    int tau = 8 + wv, mi = tau % 3, nt = tau / 3;
    f32x4 acc = (f32x4){0,0,0,0};
    #pragma unroll
    for (int ks=0; ks<2; ks++){
      f16x8 a = *(const f16x8*)&sEp[(mi*16+(lane&15))*72 + ks*32 + ((lane>>4)<<3)];
      f16x8 b = *(const f16x8*)&sGf[(nt*2+ks)*512 + lane*8];
      acc = __builtin_amdgcn_mfma_f32_16x16x32_f16(a, b, acc, 0,0,0);
    }
    #pragma unroll
    for (int reg=0; reg<4; reg++){
      int row = mi*16 + ((lane>>4)<<2) + reg;
      sFp[row*72 + nt*16 + (lane&15)] = (_Float16)acc[reg];
    }
  } else if (wv < 7){
    int mi = wv - 4;
    f32x4 acc = (f32x4){0,0,0,0};
    #pragma unroll
    for (int ks=0; ks<2; ks++){
      f16x8 a = *(const f16x8*)&sE2[(mi*16+(lane&15))*72 + ks*32 + ((lane>>4)<<3)];
      f16x8 b = *(const f16x8*)&sGf[(3*2+ks)*512 + lane*8];
      acc = __builtin_amdgcn_mfma_f32_16x16x32_f16(a, b, acc, 0,0,0);
    }
    if ((lane & 15) == 2){
      #pragma unroll
      for (int reg=0; reg<4; reg++)
        sTS[mi*16 + ((lane>>4)<<2) + reg] = acc[reg];
    }
  }
  __syncthreads();

  if (wv < 3){
    f32x4 acc = (f32x4){0,0,0,0};
    #pragma unroll
    for (int ks=0; ks<2; ks++){
      f16x8 aF = *(const f16x8*)&sFp[(wv*16+(lane&15))*72 + ks*32 + ((lane>>4)<<3)];
      f16x8 bE = *(const f16x8*)&sEp[(wv*16+(lane&15))*72 + ks*32 + ((lane>>4)<<3)];
      acc = __builtin_amdgcn_mfma_f32_16x16x32_f16(aF, bE, acc, 0,0,0);
    }
    #pragma unroll
    for (int reg=0; reg<4; reg++){
      int row = ((lane>>4)<<2) + reg;
      if (row == (lane&15)) sTd[wv*16 + row] = acc[reg];
    }
  }
  __syncthreads();

  #pragma unroll 5
  for (int j=0;j<cnt;j++){
    const int r = r0 + j;
    const int ai = aiA[j];
    float tQ  = sTd[r];
    float tS  = sTS[r];
    float den = (float)sFp[r*72 + 50];
    float dh  = (float)sFp[r*72 + ai];
    float hh  = sGd[ai];
    float hv  = (avA[j] > -1.0f) ? 1.f : 0.f;

    const int rg = i*RR + r;
    float gs = sgn[rg], gh = hgn[rg], rx = rn[rg];
    float rd = 1.f/den;
    float num = gs*(tS*rd) + hv*gh*avA[j];
    float n2  = gs*gs*(tQ*rd*rd) + hv*(2.f*gs*gh*(dh*rd) + gh*gh*hh);
    float ov  = num * rx / fmaxf(sqrtf(fmaxf(n2, 0.f)), 1e-12f);
    if (lane==0) out[((size_t)i*BC + c)*RR + r] = (r < img_len) ? ov : -1.0f;
  }
}

// ---------------------------------------------------------------------------
// Fallback path kernels (round-1 verified), used only if ws too small.
// ---------------------------------------------------------------------------
__global__ __launch_bounds__(256) void gates_kernel(
    const float* __restrict__ imgs,
    const float* __restrict__ sw1, const float* __restrict__ sb1,
    const float* __restrict__ sw2, const float* __restrict__ sb2,
    const float* __restrict__ hw1, const float* __restrict__ hb1,
    const float* __restrict__ hw2, const float* __restrict__ hb2,
    float* __restrict__ sgn, float* __restrict__ hgn, float* __restrict__ rn)
{
  __shared__ __align__(16) float xs[8*DD];
  __shared__ float red[16*256];
  __shared__ float nr[8];
  const int t = threadIdx.x;
  const int row0 = blockIdx.x * 8;
  if (t < 8) nr[t] = 0.f;
  __syncthreads();
  const float4* src = (const float4*)(imgs + (size_t)row0*DD);
  #pragma unroll
  for (int m=0;m<4;m++){
    int n = m*256+t;
    float4 v = src[n];
    ((float4*)xs)[n] = v;
    float ss = v.x*v.x+v.y*v.y+v.z*v.z+v.w*v.w;
    atomicAdd(&nr[n>>7], ss);
  }
  __syncthreads();
  float accS[8]={0,0,0,0,0,0,0,0};
  float accH[8]={0,0,0,0,0,0,0,0};
  for (int k=0;k<DD;k+=4){
    float a0=sw1[(k+0)*HH+t], a1=sw1[(k+1)*HH+t], a2=sw1[(k+2)*HH+t], a3=sw1[(k+3)*HH+t];
    float b0=hw1[(k+0)*HH+t], b1=hw1[(k+1)*HH+t], b2=hw1[(k+2)*HH+t], b3=hw1[(k+3)*HH+t];
    #pragma unroll
    for (int r=0;r<8;r++){
      float4 x = *(const float4*)&xs[r*DD+k];
      accS[r]=fmaf(x.x,a0,accS[r]); accS[r]=fmaf(x.y,a1,accS[r]);
      accS[r]=fmaf(x.z,a2,accS[r]); accS[r]=fmaf(x.w,a3,accS[r]);
      accH[r]=fmaf(x.x,b0,accH[r]); accH[r]=fmaf(x.y,b1,accH[r]);
      accH[r]=fmaf(x.z,b2,accH[r]); accH[r]=fmaf(x.w,b3,accH[r]);
    }
  }
  const float b1s=sb1[t], b1h=hb1[t], w2s=sw2[t], w2h=hw2[t];
  #pragma unroll
  for (int r=0;r<8;r++){
    red[r*256+t]     = w2s * fmaxf(accS[r]+b1s, 0.f);
    red[(8+r)*256+t] = w2h * fmaxf(accH[r]+b1h, 0.f);
  }
  __syncthreads();
  const int wv=t>>6, ln=t&63;
  #pragma unroll
  for (int q=0;q<4;q++){
    int rr_ = wv*4+q;
    float v = red[rr_*256+ln]+red[rr_*256+ln+64]+red[rr_*256+ln+128]+red[rr_*256+ln+192];
    v = wave_sum(v);
    if (ln==0) red[rr_*256] = v;
  }
  __syncthreads();
  if (t<8){
    float os = red[t*256] + sb2[0];
    float oh = red[(8+t)*256] + hb2[0];
    float s = 1.f/(1.f+__expf(-os));
    float h = 1.f/(1.f+__expf(-oh));
    float tot = s+h+1e-8f;
    sgn[row0+t] = s/tot;
    hgn[row0+t] = h/tot;
    rn[row0+t]  = 1.f/fmaxf(sqrtf(nr[t]), 1e-12f);
  }
}

__global__ __launch_bounds__(256) void gram_fb_kernel(
    const float* __restrict__ caps, float* __restrict__ G)
{
  __shared__ __align__(16) float cs[WW*CST];
  const int c    = blockIdx.x >> 2;
  const int tile = blockIdx.x & 3;
  const int w0   = tile*13;
  const int nw   = (tile==3) ? 11 : 13;
  const int t=threadIdx.x, lane=t&63, wv=t>>6;
  const int wl = lane < WW ? lane : WW-1;
  float acc[4]={0.f,0.f,0.f,0.f};
  for (int k0=0;k0<DD;k0+=128){
    __syncthreads();
    for (int n=t;n<WW*32;n+=256){
      int row=n>>5, c4=(n&31)*4;
      *(float4*)&cs[row*CST+c4] = *(const float4*)(caps + ((size_t)c*WW+row)*DD + k0 + c4);
    }
    __syncthreads();
    for (int k=0;k<128;k+=4){
      float4 cv = *(const float4*)&cs[wl*CST+k];
      #pragma unroll
      for (int q=0;q<4;q++){
        int lw = wv + q*4;
        if (lw < nw){
          float4 bv = *(const float4*)&cs[(w0+lw)*CST+k];
          acc[q]=fmaf(bv.x,cv.x,acc[q]); acc[q]=fmaf(bv.y,cv.y,acc[q]);
          acc[q]=fmaf(bv.z,cv.z,acc[q]); acc[q]=fmaf(bv.w,cv.w,acc[q]);
        }
      }
    }
  }
  if (lane < WW){
    #pragma unroll
    for (int q=0;q<4;q++){
      int lw = wv + q*4;
      if (lw < nw) G[(size_t)c*WW*WW + (w0+lw)*WW + lane] = acc[q];
    }
  }
}

__global__ __launch_bounds__(256) void pair_kernel(
    const float* __restrict__ imgs, const float* __restrict__ caps,
    const int* __restrict__ img_lens, const int* __restrict__ cap_lens,
    const float* __restrict__ sgn, const float* __restrict__ hgn,
    const float* __restrict__ rn,
    const float* __restrict__ G, float* __restrict__ out)
{
  __shared__ __align__(16) float smem[WW*CST + 52*52 + RR*52];
  float* cs = smem;
  float* Gs = smem + WW*CST;
  float* As = Gs + 52*52;
  const int bx = blockIdx.x;
  const int i = bx >> 6, c = bx & 63;
  const int t = threadIdx.x, lane = t&63;
  const int wv = __builtin_amdgcn_readfirstlane(t>>6);
  const int wl = lane < WW ? lane : WW-1;
  const int cap_len = cap_lens[c];
  const int img_len = img_lens[i];
  for (int n=t;n<52*52;n+=256){
    int w=n/52, w2=n-w*52;
    Gs[n] = (w<WW && w2<WW) ? G[(size_t)c*WW*WW + w*WW + w2] : 0.f;
  }
  float acc[9]={0,0,0,0,0,0,0,0,0};
  const float* ib = imgs + ((size_t)i*RR + wv*9)*DD;
  for (int k0=0;k0<DD;k0+=128){
    __syncthreads();
    for (int n=t;n<WW*32;n+=256){
      int row=n>>5, c4=(n&31)*4;
      *(float4*)&cs[row*CST+c4] = *(const float4*)(caps + ((size_t)c*WW+row)*DD + k0 + c4);
    }
    __syncthreads();
    for (int k=0;k<128;k+=4){
      float4 cv = *(const float4*)&cs[wl*CST+k];
      #pragma unroll
      for (int j=0;j<9;j++){
        float4 iv = *(const float4*)(ib + j*DD + k0 + k);
        acc[j]=fmaf(iv.x,cv.x,acc[j]); acc[j]=fmaf(iv.y,cv.y,acc[j]);
        acc[j]=fmaf(iv.z,cv.z,acc[j]); acc[j]=fmaf(iv.w,cv.w,acc[j]);
      }
    }
  }
  for (int j=0;j<9;j++){
    const int r = wv*9 + j;
    const float s = acc[j];
    float av; int ai;
    if (lane < cap_len){ av = s;     ai = lane; }
    else if (lane < WW){ av = -1.0f; ai = lane; }
    else               { av = -INFINITY; ai = 64; }
    #pragma unroll
    for (int off=32; off>0; off>>=1){
      float ov = __shfl_xor(av, off, 64);
      int   oi = __shfl_xor(ai, off, 64);
      if (ov > av || (ov == av && oi < ai)){ av = ov; ai = oi; }
    }
    float zv = (lane < cap_len) ? s*10.0f : -INFINITY;
    float zm = wave_max(zv);
    float e  = (lane < cap_len) ? __expf(zv - zm) : 0.f;
    float den = wave_sum(e);
    if (lane < 52) As[r*52 + lane] = (lane < WW) ? e : 0.f;
    float m = 0.f;
    #pragma unroll
    for (int g=0; g<13; g++){
      float4 ab = *(const float4*)&As[r*52 + g*4];
      m = fmaf(ab.x, Gs[(g*4+0)*52+wl], m);
      m = fmaf(ab.y, Gs[(g*4+1)*52+wl], m);
      m = fmaf(ab.z, Gs[(g*4+2)*52+wl], m);
      m = fmaf(ab.w, Gs[(g*4+3)*52+wl], m);
    }
    float tS = wave_sum(e * s);
    float tQ = wave_sum(e * m);
    float dh = __shfl(m, ai, 64);
    float hh = Gs[ai*52 + ai];
    float hv = (ai < cap_len) ? 1.f : 0.f;
    const int rg = i*RR + r;
    float gs = sgn[rg], gh = hgn[rg], rx = rn[rg];
    float rd = 1.f/den;
    float num = gs*(tS*rd) + hv*gh*av;
    float n2  = gs*gs*(tQ*rd*rd) + hv*(2.f*gs*gh*(dh*rd) + gh*gh*hh);
    float ov  = num * rx / fmaxf(sqrtf(fmaxf(n2, 0.f)), 1e-12f);
    if (lane==0) out[((size_t)i*BC + c)*RR + r] = (r < img_len) ? ov : -1.0f;
  }
}

// ---------------------------------------------------------------------------
extern "C" void kernel_launch(void* const* d_in, const int* in_sizes, int n_in,
                              void* d_out, int out_size, void* d_ws, size_t ws_size,
                              hipStream_t stream)
{
  const float* imgs = (const float*)d_in[0];
  const float* caps = (const float*)d_in[1];
  const float* sw1  = (const float*)d_in[2];
  const float* sb1  = (const float*)d_in[3];
  const float* sw2  = (const float*)d_in[4];
  const float* sb2  = (const float*)d_in[5];
  const float* hw1  = (const float*)d_in[6];
  const float* hb1  = (const float*)d_in[7];
  const float* hw2  = (const float*)d_in[8];
  const float* hb2  = (const float*)d_in[9];
  const int* img_lens = (const int*)d_in[10];
  const int* cap_lens = (const int*)d_in[11];

  char* base = (char*)d_ws;
  float*    sgn   = (float*)(base + 0);
  float*    hgn   = (float*)(base + 9216);
  float*    rn    = (float*)(base + 18432);
  float*    G     = (float*)(base + 27648);        // 640,000  -> 667,648
  _Float16* Gfrag = (_Float16*)(base + 667648);    // 524,288  -> 1,191,936
  _Float16* Ah    = (_Float16*)(base + 1191936);   // 2,359,296 -> 3,551,232
  _Float16* Al    = (_Float16*)(base + 3551232);   // 2,359,296 -> 5,910,528
  _Float16* Bh    = (_Float16*)(base + 5910528);   // 3,801,088 -> 9,711,616
  _Float16* Bl    = (_Float16*)(base + 9711616);   // 3,801,088 -> 13,512,704
  float*    H     = (float*)(base + 13512704);     // 4,718,592 -> 18,231,296
  float*    Sp    = (float*)(base + 18231296);     // 29,491,200 -> 47,722,496
  const size_t NEED = 47722496ull;

  float* out = (float*)d_out;

  if (ws_size >= NEED){
    hipLaunchKernelGGL(prepgram_kernel, dim3(1760), dim3(256), 0, stream,
                       imgs, caps, sw1, hw1, Ah, Al, Bh, Bl, G, Gfrag);
    hipLaunchKernelGGL(hgemm_kernel, dim3(72), dim3(256), 0, stream,
                       Ah, Bh, H);
    hipLaunchKernelGGL(sgemm_kernel, dim3(450), dim3(256), 0, stream,
                       Ah, Al, Bh, Bl, Sp);
    hipLaunchKernelGGL(greduce_kernel, dim3(576), dim3(256), 0, stream,
                       H, imgs, sb1, hb1, sw2, hw2, sb2, hb2, sgn, hgn, rn);
    hipLaunchKernelGGL(epi_kernel, dim3(BI*BC), dim3(512), 0, stream,
                       Sp, img_lens, cap_lens, sgn, hgn, rn, G, Gfrag, out);
  } else {
    hipLaunchKernelGGL(gates_kernel, dim3(288), dim3(256), 0, stream,
                       imgs, sw1, sb1, sw2, sb2, hw1, hb1, hw2, hb2, sgn, hgn, rn);
    hipLaunchKernelGGL(gram_fb_kernel, dim3(256), dim3(256), 0, stream, caps, G);
    hipLaunchKernelGGL(pair_kernel, dim3(BI*BC), dim3(256), 0, stream,
                       imgs, caps, img_lens, cap_lens, sgn, hgn, rn, G, out);
  }
}

// Round 15
// 197.740 us; speedup vs baseline: 1.0407x; 1.0407x over previous
//
#include <hip/hip_runtime.h>
#include <math.h>

#define BI 64
#define RR 36
#define BC 64
#define WW 50
#define DD 512
#define HH 256
#define CST 132

typedef _Float16 f16x8 __attribute__((ext_vector_type(8)));
typedef _Float16 f16x4 __attribute__((ext_vector_type(4)));
typedef float    f32x4 __attribute__((ext_vector_type(4)));

__device__ __forceinline__ float wave_sum(float v){
  #pragma unroll
  for (int off=32; off>0; off>>=1) v += __shfl_xor(v, off, 64);
  return v;
}
__device__ __forceinline__ float wave_max(float v){
  #pragma unroll
  for (int off=32; off>0; off>>=1) v = fmaxf(v, __shfl_xor(v, off, 64));
  return v;
}

// ---------------------------------------------------------------------------
// PrepGram (r13 replay-verified): fused independent producers.
//  bx < 1504 : prep3 body — split fp32 -> f16 hi + lo*2048 frags.
//  bx >= 1504: gram body — fp32 G + f16 B-frag Gfrag (ones col at n==50).
// ---------------------------------------------------------------------------
__global__ __launch_bounds__(256) void prepgram_kernel(
    const float* __restrict__ imgs, const float* __restrict__ caps,
    const float* __restrict__ sw1, const float* __restrict__ hw1,
    _Float16* __restrict__ Ah, _Float16* __restrict__ Al,
    _Float16* __restrict__ Bh, _Float16* __restrict__ Bl,
    float* __restrict__ G, _Float16* __restrict__ Gfrag)
{
  __shared__ __align__(16) float smem[WW*CST + 1024];   // gram branch only
  if (blockIdx.x < 1504){
    int u = blockIdx.x*256 + threadIdx.x;
    _Float16 *dh, *dl; int idx;
    if (u < 144*1024){ idx = u;            dh = Ah; dl = Al; }
    else             { idx = u - 144*1024; dh = Bh; dl = Bl; }
    const int tile = idx >> 10, rem = idx & 1023, ks = rem >> 6, lane = rem & 63;
    const int k0 = ks*32 + (lane >> 4)*8;
    f16x8 hv, lv;
    if (u < 144*1024 || tile < 200){
      const float* src = (u < 144*1024) ? imgs : caps;
      const int m = tile*16 + (lane & 15);
      const float* p = src + (size_t)m*DD + k0;
      #pragma unroll
      for (int j=0;j<8;j++){
        float a = p[j];
        _Float16 h = (_Float16)a;
        hv[j] = h;
        lv[j] = (_Float16)((a - (float)h) * 2048.0f);
      }
    } else {
      const int n = (tile-200)*16 + (lane & 15);          // 0..511
      const float* src = (n < HH) ? (sw1 + n) : (hw1 + n - HH);
      #pragma unroll
      for (int j=0;j<8;j++){
        float a = src[(size_t)(k0+j)*HH];
        _Float16 h = (_Float16)a;
        hv[j] = h;
        lv[j] = (_Float16)((a - (float)h) * 2048.0f);
      }
    }
    *(f16x8*)(dh + (size_t)idx*8) = hv;
    *(f16x8*)(dl + (size_t)idx*8) = lv;
  } else {
    float* cs = smem;
    float* Gt = smem + WW*CST;
    const int bxg  = blockIdx.x - 1504;
    const int c    = bxg >> 2;
    const int tile = bxg & 3;
    const int w0   = tile*16;
    const int nw   = (tile==3) ? 2 : 16;
    const int t=threadIdx.x, lane=t&63, wv=t>>6;
    const int wl = lane < WW ? lane : WW-1;
    float acc[4]={0.f,0.f,0.f,0.f};
    for (int k0=0;k0<DD;k0+=128){
      __syncthreads();
      for (int n=t;n<WW*32;n+=256){
        int row=n>>5, c4=(n&31)*4;
        *(float4*)&cs[row*CST+c4] = *(const float4*)(caps + ((size_t)c*WW+row)*DD + k0 + c4);
      }
      __syncthreads();
      for (int k=0;k<128;k+=4){
        float4 cv = *(const float4*)&cs[wl*CST+k];
        #pragma unroll
        for (int q=0;q<4;q++){
          int lw = wv + q*4;
          if (lw < nw){
            float4 bv = *(const float4*)&cs[(w0+lw)*CST+k];
            acc[q]=fmaf(bv.x,cv.x,acc[q]); acc[q]=fmaf(bv.y,cv.y,acc[q]);
            acc[q]=fmaf(bv.z,cv.z,acc[q]); acc[q]=fmaf(bv.w,cv.w,acc[q]);
          }
        }
      }
    }
    for (int n=t;n<1024;n+=256) Gt[n]=0.f;
    __syncthreads();
    if (lane < WW){
      #pragma unroll
      for (int q=0;q<4;q++){
        int lw = wv + q*4;
        if (lw < nw){
          G[(size_t)c*WW*WW + (w0+lw)*WW + lane] = acc[q];
          Gt[lw*64 + lane] = acc[q];
        }
      }
    }
    __syncthreads();
    {
      int flat = t*4;
      int ks = flat>>9, L=(flat>>3)&63, j0=flat&7;
      const bool ones = (tile==3) && ((L&15)==2);   // frag n == 50
      f16x4 v;
      #pragma unroll
      for (int e=0;e<4;e++)
        v[e] = ones ? (_Float16)1.0f
                    : (_Float16)Gt[(L&15)*64 + ks*32 + ((L>>4)<<3) + j0 + e];
      *(f16x4*)&Gfrag[(size_t)c*4096 + (tile*2+ks)*512 + L*8 + j0] = v;
    }
  }
}

// ---------------------------------------------------------------------------
// Hgemm (r12/r13 replay-verified): H = Ah @ W (raw; bias+relu in greduce).
// ---------------------------------------------------------------------------
__global__ __launch_bounds__(256) void hgemm_kernel(
    const _Float16* __restrict__ Ah, const _Float16* __restrict__ Bh,
    float* __restrict__ H)
{
  __shared__ _Float16 lds[8192];
  const int t = threadIdx.x, lane = t & 63, wv = t >> 6;
  const int mb = blockIdx.x % 18, nb = blockIdx.x / 18;
  const int wm = wv & 1, wn = wv >> 1;

  f32x4 P[4][4];
  #pragma unroll
  for (int a=0;a<4;a++)
    #pragma unroll
    for (int b=0;b<4;b++) P[a][b]=(f32x4){0,0,0,0};

  const _Float16* sbase = (wv < 2) ? Ah : (Bh + (size_t)200*8192);
  const size_t tb = (size_t)((wv < 2) ? mb : nb)*8 + (size_t)(wv & 1)*4;
  _Float16* ldst = lds + ((wv >= 2) ? 4096 : 0) + (wv & 1)*2048;

  for (int ks=0; ks<16; ks++){
    int4 v[4];
    #pragma unroll
    for (int s=0;s<4;s++)
      v[s] = *(const int4*)(sbase + (((tb+s)*16 + ks)*64 + lane)*8);
    #pragma unroll
    for (int s=0;s<4;s++)
      *(int4*)&ldst[s*512 + lane*8] = v[s];
    __syncthreads();
    f16x8 a[4], b[4];
    #pragma unroll
    for (int x=0;x<4;x++){
      a[x] = *(const f16x8*)&lds[       (wm*4+x)*512 + lane*8];
      b[x] = *(const f16x8*)&lds[4096 + (wn*4+x)*512 + lane*8];
    }
    #pragma unroll
    for (int mi=0;mi<4;mi++)
      #pragma unroll
      for (int ni=0;ni<4;ni++)
        P[mi][ni] = __builtin_amdgcn_mfma_f32_16x16x32_f16(a[mi], b[ni], P[mi][ni],0,0,0);
    __syncthreads();
  }

  const int r0 = mb*128 + wm*64 + ((lane>>4)<<2);
  const int c0 = nb*128 + wn*64 + (lane&15);
  #pragma unroll
  for (int ni=0;ni<4;ni++){
    int col = c0 + ni*16;
    #pragma unroll
    for (int mi=0;mi<4;mi++)
      #pragma unroll
      for (int reg=0;reg<4;reg++)
        H[(size_t)(r0 + mi*16 + reg)*512 + col] = P[mi][ni][reg];
  }
}

// ---------------------------------------------------------------------------
// Greduce v2 (r12/r13 replay-verified): gates from raw H (bias+relu here).
// ---------------------------------------------------------------------------
__global__ __launch_bounds__(256) void greduce_kernel(
    const float* __restrict__ H, const float* __restrict__ imgs,
    const float* __restrict__ sb1, const float* __restrict__ hb1,
    const float* __restrict__ sw2, const float* __restrict__ hw2,
    const float* __restrict__ sb2, const float* __restrict__ hb2,
    float* __restrict__ sgn, float* __restrict__ hgn, float* __restrict__ rn)
{
  const int r = blockIdx.x*4 + (threadIdx.x >> 6);
  const int lane = threadIdx.x & 63;
  float4 hs = *(const float4*)&H[(size_t)r*512 + lane*4];
  float4 bs = *(const float4*)&sb1[lane*4];
  float4 ws = *(const float4*)&sw2[lane*4];
  float4 hh = *(const float4*)&H[(size_t)r*512 + 256 + lane*4];
  float4 bh = *(const float4*)&hb1[lane*4];
  float4 wh = *(const float4*)&hw2[lane*4];
  float ds = fmaxf(hs.x+bs.x,0.f)*ws.x + fmaxf(hs.y+bs.y,0.f)*ws.y
           + fmaxf(hs.z+bs.z,0.f)*ws.z + fmaxf(hs.w+bs.w,0.f)*ws.w;
  float dh = fmaxf(hh.x+bh.x,0.f)*wh.x + fmaxf(hh.y+bh.y,0.f)*wh.y
           + fmaxf(hh.z+bh.z,0.f)*wh.z + fmaxf(hh.w+bh.w,0.f)*wh.w;
  float4 x0 = *(const float4*)&imgs[(size_t)r*512 + lane*8];
  float4 x1 = *(const float4*)&imgs[(size_t)r*512 + lane*8 + 4];
  float ss = x0.x*x0.x+x0.y*x0.y+x0.z*x0.z+x0.w*x0.w
           + x1.x*x1.x+x1.y*x1.y+x1.z*x1.z+x1.w*x1.w;
  ds = wave_sum(ds); dh = wave_sum(dh); ss = wave_sum(ss);
  if (lane == 0){
    float s = 1.f/(1.f+__expf(-(ds + sb2[0])));
    float h = 1.f/(1.f+__expf(-(dh + hb2[0])));
    float tot = s + h + 1e-8f;
    sgn[r] = s/tot; hgn[r] = h/tot;
    rn[r]  = 1.f/fmaxf(sqrtf(ss), 1e-12f);
  }
}

// ---------------------------------------------------------------------------
// S GEMM (r13 replay-verified, REVERTED from r14 hybrid): dbuf LDS (2x16KB),
// prefetch, one barrier/iter, grid 18x25=450 (co-resident at 2 blocks/CU),
// permuted Sp store. r11 (all-global) and r14 (lo-global hybrid) both
// measured worse — this all-LDS form is the empirical optimum.
// ---------------------------------------------------------------------------
__global__ __launch_bounds__(256) void sgemm_kernel(
    const _Float16* __restrict__ Ah, const _Float16* __restrict__ Al,
    const _Float16* __restrict__ Bh, const _Float16* __restrict__ Bl,
    float* __restrict__ Sp)
{
  __shared__ _Float16 lds[2*16384];
  const int t = threadIdx.x, lane = t & 63, wv = t >> 6;
  const int mb = blockIdx.x % 18, nb = blockIdx.x / 18;
  const int wm = wv & 1, wn = wv >> 1;

  f32x4 P[4][4], Q[4][4];
  #pragma unroll
  for (int a=0;a<4;a++)
    #pragma unroll
    for (int b=0;b<4;b++){ P[a][b]=(f32x4){0,0,0,0}; Q[a][b]=(f32x4){0,0,0,0}; }

  const _Float16* sbase = (wv==0)?Ah:(wv==1)?Al:(wv==2)?Bh:Bl;
  const size_t gtb = (size_t)((wv<2)? mb : nb)*8;

  int4 v[8];
  #pragma unroll
  for (int s=0;s<8;s++)
    v[s] = *(const int4*)(sbase + (((gtb+s)*16 + 0)*64 + lane)*8);
  {
    _Float16* ldst = lds + wv*4096;
    #pragma unroll
    for (int s=0;s<8;s++)
      *(int4*)&ldst[s*512 + lane*8] = v[s];
  }
  __syncthreads();

  for (int ks=0; ks<16; ks++){
    if (ks < 15){
      #pragma unroll
      for (int s=0;s<8;s++)
        v[s] = *(const int4*)(sbase + (((gtb+s)*16 + (ks+1))*64 + lane)*8);
    }

    const _Float16* L = lds + (ks & 1)*16384;
    f16x8 a_h[4], a_l[4], b_h[4], b_l[4];
    #pragma unroll
    for (int x=0;x<4;x++){
      a_h[x] = *(const f16x8*)&L[        (wm*4+x)*512 + lane*8];
      a_l[x] = *(const f16x8*)&L[ 4096 + (wm*4+x)*512 + lane*8];
      b_h[x] = *(const f16x8*)&L[ 8192 + (wn*4+x)*512 + lane*8];
      b_l[x] = *(const f16x8*)&L[12288 + (wn*4+x)*512 + lane*8];
    }
    #pragma unroll
    for (int mi=0;mi<4;mi++)
      #pragma unroll
      for (int ni=0;ni<4;ni++){
        P[mi][ni] = __builtin_amdgcn_mfma_f32_16x16x32_f16(a_h[mi], b_h[ni], P[mi][ni],0,0,0);
        Q[mi][ni] = __builtin_amdgcn_mfma_f32_16x16x32_f16(a_h[mi], b_l[ni], Q[mi][ni],0,0,0);
        Q[mi][ni] = __builtin_amdgcn_mfma_f32_16x16x32_f16(a_l[mi], b_h[ni], Q[mi][ni],0,0,0);
      }

    if (ks < 15){
      _Float16* ldst = lds + ((ks+1) & 1)*16384 + wv*4096;
      #pragma unroll
      for (int s=0;s<8;s++)
        *(int4*)&ldst[s*512 + lane*8] = v[s];
    }
    __syncthreads();
  }

  const int r0 = mb*128 + wm*64 + ((lane>>4)<<2);
  const int c0 = nb*128 + wn*64 + (lane&15);
  size_t pr[16]; size_t pc[4];
  #pragma unroll
  for (int mi=0;mi<4;mi++)
    #pragma unroll
    for (int reg=0;reg<4;reg++){
      unsigned row = (unsigned)(r0 + mi*16 + reg);
      unsigned i = row / 36u, rr_ = row - i*36u;
      pr[mi*4+reg] = (size_t)i*115200u + (size_t)rr_*50u;
    }
  #pragma unroll
  for (int ni=0;ni<4;ni++){
    unsigned col = (unsigned)(c0 + ni*16);
    unsigned cc = col / 50u, w = col - cc*50u;
    pc[ni] = (size_t)cc*1800u + w;
  }
  #pragma unroll
  for (int mi=0;mi<4;mi++)
    #pragma unroll
    for (int ni=0;ni<4;ni++)
      #pragma unroll
      for (int reg=0;reg<4;reg++)
        Sp[pr[mi*4+reg] + pc[ni]] =
            P[mi][ni][reg] + Q[mi][ni][reg]*(1.0f/2048.0f);
}

// ---------------------------------------------------------------------------
// Epilogue v3 (r8..r13 replay-verified, verbatim).
// ---------------------------------------------------------------------------
__global__ __launch_bounds__(512) void epi_kernel(
    const float* __restrict__ Sp,
    const int* __restrict__ img_lens, const int* __restrict__ cap_lens,
    const float* __restrict__ sgn, const float* __restrict__ hgn,
    const float* __restrict__ rn,
    const float* __restrict__ G, const _Float16* __restrict__ Gfrag,
    float* __restrict__ out)
{
  __shared__ __align__(16) _Float16 sEp[48*72];
  __shared__ __align__(16) _Float16 sE2[48*72];
  __shared__ __align__(16) _Float16 sFp[48*72];
  __shared__ __align__(16) _Float16 sGf[4096];
  __shared__ float sTd[48];
  __shared__ float sTS[48];
  __shared__ float sGd[64];

  const int bx = blockIdx.x;
  const int i = bx >> 6, c = bx & 63;
  const int t = threadIdx.x, lane = t & 63;
  const int wv = __builtin_amdgcn_readfirstlane(t >> 6);   // 0..7
  const int cap_len = cap_lens[c];
  const int img_len = img_lens[i];

  ((int4*)sGf)[t] = ((const int4*)(Gfrag + (size_t)c*4096))[t];
  if (t < WW) sGd[t] = G[(size_t)c*WW*WW + t*(WW+1)];
  if (t < 96){
    int row = 36 + (t>>3), col8 = (t&7)*8;
    *(int4*)&sEp[row*72 + col8] = (int4){0,0,0,0};
    *(int4*)&sE2[row*72 + col8] = (int4){0,0,0,0};
  }

  const int r0  = (wv < 4) ? wv*5 : 20 + (wv-4)*4;
  const int cnt = (wv < 4) ? 5 : 4;

  const float* srow = Sp + (size_t)(i*64 + c)*1800u + (size_t)r0*50;
  float avA[5]; int aiA[5];
  #pragma unroll 5
  for (int j=0;j<cnt;j++){
    const int r = r0 + j;
    float s = (lane < WW) ? srow[j*50 + lane] : 0.f;
    const bool valid = (lane < cap_len);
    float av = wave_max(valid ? s : -INFINITY);
    unsigned long long m = __ballot(valid && (s == av));
    int ai = (int)(__ffsll((long long)m) - 1);
    float e = valid ? __expf(10.0f*(s - av)) : 0.f;
    avA[j] = av; aiA[j] = ai;
    sEp[r*72 + lane] = (_Float16)e;
    sE2[r*72 + lane] = (_Float16)(e * s);
  }
  __syncthreads();

  {
    int mi = wv % 3, nt = wv / 3;
    f32x4 acc = (f32x4){0,0,0,0};
    #pragma unroll
    for (int ks=0; ks<2; ks++){
      f16x8 a = *(const f16x8*)&sEp[(mi*16+(lane&15))*72 + ks*32 + ((lane>>4)<<3)];
      f16x8 b = *(const f16x8*)&sGf[(nt*2+ks)*512 + lane*8];
      acc = __builtin_amdgcn_mfma_f32_16x16x32_f16(a, b, acc, 0,0,0);
    }
    #pragma unroll
    for (int reg=0; reg<4; reg++){
      int row = mi*16 + ((lane>>4)<<2) + reg;
      sFp[row*72 + nt*16 + (lane&15)] = (_Float16)acc[reg];
    }
  }
  if (wv < 4){
    int tau = 8 + wv, mi = tau % 3, nt = tau / 3;
    f32x4 acc = (f32x4){0,0,0,0};
    #pragma unroll
    for (int ks=0; ks<2; ks++){
      f16x8 a = *(const f16x8*)&sEp[(mi*16+(lane&15))*72 + ks*32 + ((lane>>4)<<3)];
      f16x8 b = *(const f16x8*)&sGf[(nt*2+ks)*512 + lane*8];
      acc = __builtin_amdgcn_mfma_f32_16x16x32_f16(a, b, acc, 0,0,0);
    }
    #pragma unroll
    for (int reg=0; reg<4; reg++){
      int row = mi*16 + ((lane>>4)<<2) + reg;
      sFp[row*72 + nt*16 + (lane&15)] = (_Float16)acc[reg];
    }
  } else if (wv < 7){
    int mi = wv - 4;
    f32x4 acc = (f32x4){0,0,0,0};
    #pragma unroll
    for (int ks=0; ks<2; ks++){
      f16x8 a = *(const f16x8*)&sE2[(mi*16+(lane&15))*72 + ks*32 + ((lane>>4)<<3)];
      f16x8 b = *(const f16x8*)&sGf[(3*2+ks)*512 + lane*8];
      acc = __builtin_amdgcn_mfma_f32_16x16x32_f16(a, b, acc, 0,0,0);
    }
    if ((lane & 15) == 2){
      #pragma unroll
      for (int reg=0; reg<4; reg++)
        sTS[mi*16 + ((lane>>4)<<2) + reg] = acc[reg];
    }
  }
  __syncthreads();

  if (wv < 3){
    f32x4 acc = (f32x4){0,0,0,0};
    #pragma unroll
    for (int ks=0; ks<2; ks++){
      f16x8 aF = *(const f16x8*)&sFp[(wv*16+(lane&15))*72 + ks*32 + ((lane>>4)<<3)];
      f16x8 bE = *(const f16x8*)&sEp[(wv*16+(lane&15))*72 + ks*32 + ((lane>>4)<<3)];
      acc = __builtin_amdgcn_mfma_f32_16x16x32_f16(aF, bE, acc, 0,0,0);
    }
    #pragma unroll
    for (int reg=0; reg<4; reg++){
      int row = ((lane>>4)<<2) + reg;
      if (row == (lane&15)) sTd[wv*16 + row] = acc[reg];
    }
  }
  __syncthreads();

  #pragma unroll 5
  for (int j=0;j<cnt;j++){
    const int r = r0 + j;
    const int ai = aiA[j];
    float tQ  = sTd[r];
    float tS  = sTS[r];
    float den = (float)sFp[r*72 + 50];
    float dh  = (float)sFp[r*72 + ai];
    float hh  = sGd[ai];
    float hv  = (avA[j] > -1.0f) ? 1.f : 0.f;

    const int rg = i*RR + r;
    float gs = sgn[rg], gh = hgn[rg], rx = rn[rg];
    float rd = 1.f/den;
    float num = gs*(tS*rd) + hv*gh*avA[j];
    float n2  = gs*gs*(tQ*rd*rd) + hv*(2.f*gs*gh*(dh*rd) + gh*gh*hh);
    float ov  = num * rx / fmaxf(sqrtf(fmaxf(n2, 0.f)), 1e-12f);
    if (lane==0) out[((size_t)i*BC + c)*RR + r] = (r < img_len) ? ov : -1.0f;
  }
}

// ---------------------------------------------------------------------------
// Fallback path kernels (round-1 verified), used only if ws too small.
// ---------------------------------------------------------------------------
__global__ __launch_bounds__(256) void gates_kernel(
    const float* __restrict__ imgs,
    const float* __restrict__ sw1, const float* __restrict__ sb1,
    const float* __restrict__ sw2, const float* __restrict__ sb2,
    const float* __restrict__ hw1, const float* __restrict__ hb1,
    const float* __restrict__ hw2, const float* __restrict__ hb2,
    float* __restrict__ sgn, float* __restrict__ hgn, float* __restrict__ rn)
{
  __shared__ __align__(16) float xs[8*DD];
  __shared__ float red[16*256];
  __shared__ float nr[8];
  const int t = threadIdx.x;
  const int row0 = blockIdx.x * 8;
  if (t < 8) nr[t] = 0.f;
  __syncthreads();
  const float4* src = (const float4*)(imgs + (size_t)row0*DD);
  #pragma unroll
  for (int m=0;m<4;m++){
    int n = m*256+t;
    float4 v = src[n];
    ((float4*)xs)[n] = v;
    float ss = v.x*v.x+v.y*v.y+v.z*v.z+v.w*v.w;
    atomicAdd(&nr[n>>7], ss);
  }
  __syncthreads();
  float accS[8]={0,0,0,0,0,0,0,0};
  float accH[8]={0,0,0,0,0,0,0,0};
  for (int k=0;k<DD;k+=4){
    float a0=sw1[(k+0)*HH+t], a1=sw1[(k+1)*HH+t], a2=sw1[(k+2)*HH+t], a3=sw1[(k+3)*HH+t];
    float b0=hw1[(k+0)*HH+t], b1=hw1[(k+1)*HH+t], b2=hw1[(k+2)*HH+t], b3=hw1[(k+3)*HH+t];
    #pragma unroll
    for (int r=0;r<8;r++){
      float4 x = *(const float4*)&xs[r*DD+k];
      accS[r]=fmaf(x.x,a0,accS[r]); accS[r]=fmaf(x.y,a1,accS[r]);
      accS[r]=fmaf(x.z,a2,accS[r]); accS[r]=fmaf(x.w,a3,accS[r]);
      accH[r]=fmaf(x.x,b0,accH[r]); accH[r]=fmaf(x.y,b1,accH[r]);
      accH[r]=fmaf(x.z,b2,accH[r]); accH[r]=fmaf(x.w,b3,accH[r]);
    }
  }
  const float b1s=sb1[t], b1h=hb1[t], w2s=sw2[t], w2h=hw2[t];
  #pragma unroll
  for (int r=0;r<8;r++){
    red[r*256+t]     = w2s * fmaxf(accS[r]+b1s, 0.f);
    red[(8+r)*256+t] = w2h * fmaxf(accH[r]+b1h, 0.f);
  }
  __syncthreads();
  const int wv=t>>6, ln=t&63;
  #pragma unroll
  for (int q=0;q<4;q++){
    int rr_ = wv*4+q;
    float v = red[rr_*256+ln]+red[rr_*256+ln+64]+red[rr_*256+ln+128]+red[rr_*256+ln+192];
    v = wave_sum(v);
    if (ln==0) red[rr_*256] = v;
  }
  __syncthreads();
  if (t<8){
    float os = red[t*256] + sb2[0];
    float oh = red[(8+t)*256] + hb2[0];
    float s = 1.f/(1.f+__expf(-os));
    float h = 1.f/(1.f+__expf(-oh));
    float tot = s+h+1e-8f;
    sgn[row0+t] = s/tot;
    hgn[row0+t] = h/tot;
    rn[row0+t]  = 1.f/fmaxf(sqrtf(nr[t]), 1e-12f);
  }
}

__global__ __launch_bounds__(256) void gram_fb_kernel(
    const float* __restrict__ caps, float* __restrict__ G)
{
  __shared__ __align__(16) float cs[WW*CST];
  const int c    = blockIdx.x >> 2;
  const int tile = blockIdx.x & 3;
  const int w0   = tile*13;
  const int nw   = (tile==3) ? 11 : 13;
  const int t=threadIdx.x, lane=t&63, wv=t>>6;
  const int wl = lane < WW ? lane : WW-1;
  float acc[4]={0.f,0.f,0.f,0.f};
  for (int k0=0;k0<DD;k0+=128){
    __syncthreads();
    for (int n=t;n<WW*32;n+=256){
      int row=n>>5, c4=(n&31)*4;
      *(float4*)&cs[row*CST+c4] = *(const float4*)(caps + ((size_t)c*WW+row)*DD + k0 + c4);
    }
    __syncthreads();
    for (int k=0;k<128;k+=4){
      float4 cv = *(const float4*)&cs[wl*CST+k];
      #pragma unroll
      for (int q=0;q<4;q++){
        int lw = wv + q*4;
        if (lw < nw){
          float4 bv = *(const float4*)&cs[(w0+lw)*CST+k];
          acc[q]=fmaf(bv.x,cv.x,acc[q]); acc[q]=fmaf(bv.y,cv.y,acc[q]);
          acc[q]=fmaf(bv.z,cv.z,acc[q]); acc[q]=fmaf(bv.w,cv.w,acc[q]);
        }
      }
    }
  }
  if (lane < WW){
    #pragma unroll
    for (int q=0;q<4;q++){
      int lw = wv + q*4;
      if (lw < nw) G[(size_t)c*WW*WW + (w0+lw)*WW + lane] = acc[q];
    }
  }
}

__global__ __launch_bounds__(256) void pair_kernel(
    const float* __restrict__ imgs, const float* __restrict__ caps,
    const int* __restrict__ img_lens, const int* __restrict__ cap_lens,
    const float* __restrict__ sgn, const float* __restrict__ hgn,
    const float* __restrict__ rn,
    const float* __restrict__ G, float* __restrict__ out)
{
  __shared__ __align__(16) float smem[WW*CST + 52*52 + RR*52];
  float* cs = smem;
  float* Gs = smem + WW*CST;
  float* As = Gs + 52*52;
  const int bx = blockIdx.x;
  const int i = bx >> 6, c = bx & 63;
  const int t = threadIdx.x, lane = t&63;
  const int wv = __builtin_amdgcn_readfirstlane(t>>6);
  const int wl = lane < WW ? lane : WW-1;
  const int cap_len = cap_lens[c];
  const int img_len = img_lens[i];
  for (int n=t;n<52*52;n+=256){
    int w=n/52, w2=n-w*52;
    Gs[n] = (w<WW && w2<WW) ? G[(size_t)c*WW*WW + w*WW + w2] : 0.f;
  }
  float acc[9]={0,0,0,0,0,0,0,0,0};
  const float* ib = imgs + ((size_t)i*RR + wv*9)*DD;
  for (int k0=0;k0<DD;k0+=128){
    __syncthreads();
    for (int n=t;n<WW*32;n+=256){
      int row=n>>5, c4=(n&31)*4;
      *(float4*)&cs[row*CST+c4] = *(const float4*)(caps + ((size_t)c*WW+row)*DD + k0 + c4);
    }
    __syncthreads();
    for (int k=0;k<128;k+=4){
      float4 cv = *(const float4*)&cs[wl*CST+k];
      #pragma unroll
      for (int j=0;j<9;j++){
        float4 iv = *(const float4*)(ib + j*DD + k0 + k);
        acc[j]=fmaf(iv.x,cv.x,acc[j]); acc[j]=fmaf(iv.y,cv.y,acc[j]);
        acc[j]=fmaf(iv.z,cv.z,acc[j]); acc[j]=fmaf(iv.w,cv.w,acc[j]);
      }
    }
  }
  for (int j=0;j<9;j++){
    const int r = wv*9 + j;
    const float s = acc[j];
    float av; int ai;
    if (lane < cap_len){ av = s;     ai = lane; }
    else if (lane < WW){ av = -1.0f; ai = lane; }
    else               { av = -INFINITY; ai = 64; }
    #pragma unroll
    for (int off=32; off>0; off>>=1){
      float ov = __shfl_xor(av, off, 64);
      int   oi = __shfl_xor(ai, off, 64);
      if (ov > av || (ov == av && oi < ai)){ av = ov; ai = oi; }
    }
    float zv = (lane < cap_len) ? s*10.0f : -INFINITY;
    float zm = wave_max(zv);
    float e  = (lane < cap_len) ? __expf(zv - zm) : 0.f;
    float den = wave_sum(e);
    if (lane < 52) As[r*52 + lane] = (lane < WW) ? e : 0.f;
    float m = 0.f;
    #pragma unroll
    for (int g=0; g<13; g++){
      float4 ab = *(const float4*)&As[r*52 + g*4];
      m = fmaf(ab.x, Gs[(g*4+0)*52+wl], m);
      m = fmaf(ab.y, Gs[(g*4+1)*52+wl], m);
      m = fmaf(ab.z, Gs[(g*4+2)*52+wl], m);
      m = fmaf(ab.w, Gs[(g*4+3)*52+wl], m);
    }
    float tS = wave_sum(e * s);
    float tQ = wave_sum(e * m);
    float dh = __shfl(m, ai, 64);
    float hh = Gs[ai*52 + ai];
    float hv = (ai < cap_len) ? 1.f : 0.f;
    const int rg = i*RR + r;
    float gs = sgn[rg], gh = hgn[rg], rx = rn[rg];
    float rd = 1.f/den;
    float num = gs*(tS*rd) + hv*gh*av;
    float n2  = gs*gs*(tQ*rd*rd) + hv*(2.f*gs*gh*(dh*rd) + gh*gh*hh);
    float ov  = num * rx / fmaxf(sqrtf(fmaxf(n2, 0.f)), 1e-12f);
    if (lane==0) out[((size_t)i*BC + c)*RR + r] = (r < img_len) ? ov : -1.0f;
  }
}

// ---------------------------------------------------------------------------
extern "C" void kernel_launch(void* const* d_in, const int* in_sizes, int n_in,
                              void* d_out, int out_size, void* d_ws, size_t ws_size,
                              hipStream_t stream)
{
  const float* imgs = (const float*)d_in[0];
  const float* caps = (const float*)d_in[1];
  const float* sw1  = (const float*)d_in[2];
  const float* sb1  = (const float*)d_in[3];
  const float* sw2  = (const float*)d_in[4];
  const float* sb2  = (const float*)d_in[5];
  const float* hw1  = (const float*)d_in[6];
  const float* hb1  = (const float*)d_in[7];
  const float* hw2  = (const float*)d_in[8];
  const float* hb2  = (const float*)d_in[9];
  const int* img_lens = (const int*)d_in[10];
  const int* cap_lens = (const int*)d_in[11];

  char* base = (char*)d_ws;
  float*    sgn   = (float*)(base + 0);
  float*    hgn   = (float*)(base + 9216);
  float*    rn    = (float*)(base + 18432);
  float*    G     = (float*)(base + 27648);        // 640,000  -> 667,648
  _Float16* Gfrag = (_Float16*)(base + 667648);    // 524,288  -> 1,191,936
  _Float16* Ah    = (_Float16*)(base + 1191936);   // 2,359,296 -> 3,551,232
  _Float16* Al    = (_Float16*)(base + 3551232);   // 2,359,296 -> 5,910,528
  _Float16* Bh    = (_Float16*)(base + 5910528);   // 3,801,088 -> 9,711,616
  _Float16* Bl    = (_Float16*)(base + 9711616);   // 3,801,088 -> 13,512,704
  float*    H     = (float*)(base + 13512704);     // 4,718,592 -> 18,231,296
  float*    Sp    = (float*)(base + 18231296);     // 29,491,200 -> 47,722,496
  const size_t NEED = 47722496ull;

  float* out = (float*)d_out;

  if (ws_size >= NEED){
    hipLaunchKernelGGL(prepgram_kernel, dim3(1760), dim3(256), 0, stream,
                       imgs, caps, sw1, hw1, Ah, Al, Bh, Bl, G, Gfrag);
    hipLaunchKernelGGL(hgemm_kernel, dim3(72), dim3(256), 0, stream,
                       Ah, Bh, H);
    hipLaunchKernelGGL(sgemm_kernel, dim3(450), dim3(256), 0, stream,
                       Ah, Al, Bh, Bl, Sp);
    hipLaunchKernelGGL(greduce_kernel, dim3(576), dim3(256), 0, stream,
                       H, imgs, sb1, hb1, sw2, hw2, sb2, hb2, sgn, hgn, rn);
    hipLaunchKernelGGL(epi_kernel, dim3(BI*BC), dim3(512), 0, stream,
                       Sp, img_lens, cap_lens, sgn, hgn, rn, G, Gfrag, out);
  } else {
    hipLaunchKernelGGL(gates_kernel, dim3(288), dim3(256), 0, stream,
                       imgs, sw1, sb1, sw2, sb2, hw1, hb1, hw2, hb2, sgn, hgn, rn);
    hipLaunchKernelGGL(gram_fb_kernel, dim3(256), dim3(256), 0, stream, caps, G);
    hipLaunchKernelGGL(pair_kernel, dim3(BI*BC), dim3(256), 0, stream,
                       imgs, caps, img_lens, cap_lens, sgn, hgn, rn, G, out);
  }
}